// Round 1
// baseline (1054.163 us; speedup 1.0000x reference)
//
#include <hip/hip_runtime.h>
#include <stdint.h>

#define NROWS 65536
#define DIM   512
#define KC    1024

// ---------------- workspace layout ----------------
// [0, 256KB)        best_idx  int[65536]
// [256KB, +4KB)     wnorm     float[1024]
// [260KB, +4KB)     counts    int[1024]
// [264KB, +8)       sumX2     double
// [264KB+8, +8)     sumS      double

// ---------------- wnorm: ||w_k||^2 ----------------
__global__ __launch_bounds__(256) void wnorm_kernel(const float* __restrict__ W,
                                                    float* __restrict__ wnorm) {
  int code = blockIdx.x * 4 + (threadIdx.x >> 6);
  int lane = threadIdx.x & 63;
  const float* wr = W + code * DIM;
  float s = 0.f;
#pragma unroll
  for (int j = 0; j < DIM / 64; ++j) {
    float v = wr[lane + j * 64];
    s = fmaf(v, v, s);
  }
#pragma unroll
  for (int off = 32; off; off >>= 1) s += __shfl_xor(s, off, 64);
  if (lane == 0) wnorm[code] = s;
}

// ---------------- sum of x^2 over all inputs ----------------
__global__ __launch_bounds__(256) void sumx2_kernel(const float4* __restrict__ X4,
                                                    double* __restrict__ sumX2) {
  int i0 = blockIdx.x * blockDim.x + threadIdx.x;
  int stride = gridDim.x * blockDim.x;
  const int total = NROWS * DIM / 4;
  double acc = 0.0;
  for (int i = i0; i < total; i += stride) {
    float4 v = X4[i];
    acc += (double)v.x * v.x + (double)v.y * v.y + (double)v.z * v.z + (double)v.w * v.w;
  }
#pragma unroll
  for (int off = 32; off; off >>= 1) acc += __shfl_xor(acc, off, 64);
  if ((threadIdx.x & 63) == 0) atomicAdd(sumX2, acc);
}

// ---------------- main: distances + argmin ----------------
// score_k(row) = ||w_k||^2 - 2 * dot(x_row, w_k)   (drop constant ||x||^2)
#define BM 128
#define BN 128
#define BKT 16
#define TM 8
#define TN 8
#define LDA (BM + 4)   // pad: conflict-free transposed stores, 16B-aligned rows

__global__ __launch_bounds__(256) void dist_argmin_kernel(
    const float* __restrict__ X, const float* __restrict__ W,
    const float* __restrict__ wnorm, int* __restrict__ best_idx,
    int* __restrict__ counts, double* __restrict__ sumS) {
  __shared__ float As[BKT][LDA];
  __shared__ float Bs[BKT][LDA];
  const int t = threadIdx.x;
  const int row0 = blockIdx.x * BM;
  const int rg = t >> 4;   // 0..15 row group (8 rows each)
  const int cg = t & 15;   // 0..15 col group (8 codes each)

  unsigned long long best[TM];
#pragma unroll
  for (int i = 0; i < TM; ++i) best[i] = ~0ull;

  for (int kc = 0; kc < KC; kc += BN) {
    float acc[TM][TN];
#pragma unroll
    for (int i = 0; i < TM; ++i)
#pragma unroll
      for (int j = 0; j < TN; ++j) acc[i][j] = 0.f;

    for (int d0 = 0; d0 < DIM; d0 += BKT) {
      __syncthreads();
#pragma unroll
      for (int h = 0; h < 2; ++h) {
        int q = t + h * 256;         // 0..511 float4 slots
        int r = q >> 2;              // 0..127
        int c4 = (q & 3) * 4;        // 0,4,8,12
        float4 va = *(const float4*)&X[(size_t)(row0 + r) * DIM + d0 + c4];
        float4 vb = *(const float4*)&W[(size_t)(kc + r) * DIM + d0 + c4];
        As[c4 + 0][r] = va.x; As[c4 + 1][r] = va.y;
        As[c4 + 2][r] = va.z; As[c4 + 3][r] = va.w;
        Bs[c4 + 0][r] = vb.x; Bs[c4 + 1][r] = vb.y;
        Bs[c4 + 2][r] = vb.z; Bs[c4 + 3][r] = vb.w;
      }
      __syncthreads();
#pragma unroll
      for (int dd = 0; dd < BKT; ++dd) {
        float a[TM], b[TN];
#pragma unroll
        for (int i = 0; i < TM; ++i) a[i] = As[dd][rg * TM + i];
#pragma unroll
        for (int j = 0; j < TN; ++j) b[j] = Bs[dd][cg * TN + j];
#pragma unroll
        for (int i = 0; i < TM; ++i)
#pragma unroll
          for (int j = 0; j < TN; ++j) acc[i][j] = fmaf(a[i], b[j], acc[i][j]);
      }
    }
    // fold this chunk of codes into the running argmin
#pragma unroll
    for (int j = 0; j < TN; ++j) {
      int k = kc + cg * TN + j;
      float wn = wnorm[k];
#pragma unroll
      for (int i = 0; i < TM; ++i) {
        float s = fmaf(-2.0f, acc[i][j], wn);
        unsigned u = __float_as_uint(s);
        unsigned key = (u & 0x80000000u) ? ~u : (u | 0x80000000u);  // monotone map
        unsigned long long p = ((unsigned long long)key << 32) | (unsigned)k;
        if (p < best[i]) best[i] = p;   // ties -> smaller index (numpy argmin)
      }
    }
  }
  // reduce across the 16 col-group lanes
#pragma unroll
  for (int off = 8; off; off >>= 1) {
#pragma unroll
    for (int i = 0; i < TM; ++i) {
      unsigned long long o = __shfl_xor(best[i], off, 16);
      if (o < best[i]) best[i] = o;
    }
  }
  if (cg == 0) {
    double local = 0.0;
#pragma unroll
    for (int i = 0; i < TM; ++i) {
      int row = row0 + rg * TM + i;
      unsigned key = (unsigned)(best[i] >> 32);
      int k = (int)(best[i] & 0xffffffffu);
      best_idx[row] = k;
      atomicAdd(&counts[k], 1);
      unsigned u = (key & 0x80000000u) ? (key ^ 0x80000000u) : ~key;
      local += (double)__uint_as_float(u);
    }
    atomicAdd(sumS, local);
  }
}

// ---------------- finalize: loss + perplexity ----------------
__global__ __launch_bounds__(256) void finalize_kernel(
    const int* __restrict__ counts, const double* __restrict__ sumX2,
    const double* __restrict__ sumS, float* __restrict__ out_loss,
    float* __restrict__ out_perp) {
  __shared__ float red[4];
  int t = threadIdx.x;
  float h = 0.f;
  for (int k = t; k < KC; k += 256) {
    float p = (float)counts[k] / (float)NROWS;
    h -= p * logf(p + 1e-10f);
  }
#pragma unroll
  for (int off = 32; off; off >>= 1) h += __shfl_xor(h, off, 64);
  if ((t & 63) == 0) red[t >> 6] = h;
  __syncthreads();
  if (t == 0) {
    float H = red[0] + red[1] + red[2] + red[3];
    *out_perp = expf(H);
    double m = (*sumX2 + *sumS) / (double)((long long)NROWS * DIM);
    *out_loss = (float)(1.25 * m);
  }
}

// ---------------- quantized_st = W[best_idx] (scalar: d_out+1 is unaligned) --
__global__ __launch_bounds__(256) void quant_kernel(const float* __restrict__ W,
                                                    const int* __restrict__ best_idx,
                                                    float* __restrict__ out) {
  int i0 = blockIdx.x * blockDim.x + threadIdx.x;
  int stride = gridDim.x * blockDim.x;
  const int total = NROWS * DIM;
  for (int i = i0; i < total; i += stride) {
    int row = i >> 9;       // /512
    int d = i & 511;
    out[i] = W[best_idx[row] * DIM + d];
  }
}

// ---------------- encodings one-hot (float2-aligned at its offset) ----------
__global__ __launch_bounds__(256) void enc_kernel(const int* __restrict__ best_idx,
                                                  float2* __restrict__ out2) {
  int i0 = blockIdx.x * blockDim.x + threadIdx.x;
  int stride = gridDim.x * blockDim.x;
  const int total = NROWS * (KC / 2);
  for (int i = i0; i < total; i += stride) {
    int row = i >> 9;       // 512 float2 per row
    int c2 = i & 511;
    int k = best_idx[row];
    float2 v = {0.f, 0.f};
    if ((k >> 1) == c2) {
      if (k & 1) v.y = 1.0f; else v.x = 1.0f;
    }
    out2[i] = v;
  }
}

extern "C" void kernel_launch(void* const* d_in, const int* in_sizes, int n_in,
                              void* d_out, int out_size, void* d_ws, size_t ws_size,
                              hipStream_t stream) {
  const float* X = (const float*)d_in[0];
  const float* W = (const float*)d_in[1];
  float* out = (float*)d_out;
  char* ws = (char*)d_ws;

  int* best_idx   = (int*)ws;
  float* wnorm    = (float*)(ws + (256 << 10));
  int* counts     = (int*)(ws + (260 << 10));
  double* sumX2   = (double*)(ws + (264 << 10));
  double* sumS    = (double*)(ws + (264 << 10) + 8);

  float* out_loss = out;                       // [0]
  float* quant    = out + 1;                   // [1 .. 1+N*D)
  float* out_perp = out + 1 + NROWS * DIM;     // [33554433]
  float2* enc2    = (float2*)(out + 2 + NROWS * DIM);  // 8B-aligned

  hipMemsetAsync(ws + (260 << 10), 0, 4096 + 16, stream);  // counts + sums

  wnorm_kernel<<<KC / 4, 256, 0, stream>>>(W, wnorm);
  sumx2_kernel<<<2048, 256, 0, stream>>>((const float4*)X, sumX2);
  dist_argmin_kernel<<<NROWS / BM, 256, 0, stream>>>(X, W, wnorm, best_idx,
                                                     counts, sumS);
  finalize_kernel<<<1, 256, 0, stream>>>(counts, sumX2, sumS, out_loss, out_perp);
  quant_kernel<<<8192, 256, 0, stream>>>(W, best_idx, quant);
  enc_kernel<<<8192, 256, 0, stream>>>(best_idx, enc2);
}

// Round 2
// 398.302 us; speedup vs baseline: 2.6466x; 2.6466x over previous
//
#include <hip/hip_runtime.h>
#include <stdint.h>

typedef unsigned short u16;
typedef unsigned long long u64;

#define NROWS 65536
#define DIM   512
#define KC    1024

#define GLOBAL_AS __attribute__((address_space(1)))
#define LDS_AS    __attribute__((address_space(3)))

__device__ __forceinline__ void gload_lds16(const void* g, void* l) {
  __builtin_amdgcn_global_load_lds((const GLOBAL_AS uint32_t*)g,
                                   (LDS_AS uint32_t*)l, 16, 0, 0);
}

__device__ __forceinline__ u16 f2bf(float f) {  // RNE float->bf16 bits
  unsigned u = __float_as_uint(f);
  return (u16)((u + 0x7fffu + ((u >> 16) & 1u)) >> 16);
}

// ---- convert X -> bf16 (hi) + exact sum(x^2) in fp64 ----------------------
__global__ __launch_bounds__(256) void convx_kernel(const float4* __restrict__ X4,
                                                    ushort4* __restrict__ Xh4,
                                                    double* __restrict__ sumX2) {
  int i0 = blockIdx.x * blockDim.x + threadIdx.x;
  int stride = gridDim.x * blockDim.x;
  const int total = NROWS * DIM / 4;
  double acc = 0.0;
  for (int i = i0; i < total; i += stride) {
    float4 v = X4[i];
    acc += (double)v.x * v.x + (double)v.y * v.y + (double)v.z * v.z + (double)v.w * v.w;
    ushort4 h;
    h.x = f2bf(v.x); h.y = f2bf(v.y); h.z = f2bf(v.z); h.w = f2bf(v.w);
    Xh4[i] = h;
  }
#pragma unroll
  for (int off = 32; off; off >>= 1) acc += __shfl_xor(acc, off, 64);
  if ((threadIdx.x & 63) == 0) atomicAdd(sumX2, acc);
}

// ---- convert W -> bf16 + exact ||w_k||^2 ----------------------------------
__global__ __launch_bounds__(256) void wprep_kernel(const float* __restrict__ W,
                                                    u16* __restrict__ Wh,
                                                    float* __restrict__ wnorm) {
  int code = blockIdx.x * 4 + (threadIdx.x >> 6);
  int lane = threadIdx.x & 63;
  const float* wr = W + code * DIM;
  u16* wh = Wh + code * DIM;
  float s = 0.f;
#pragma unroll
  for (int j = 0; j < DIM / 64; ++j) {
    float v = wr[lane + j * 64];
    s = fmaf(v, v, s);
    wh[lane + j * 64] = f2bf(v);
  }
#pragma unroll
  for (int off = 32; off; off >>= 1) s += __shfl_xor(s, off, 64);
  if (lane == 0) wnorm[code] = s;
}

// ---- main: bf16 MFMA GEMM (scores) + fused argmin -------------------------
// score_k(row) = ||w_k||^2_exact - 2 * dot_bf16(x_row, w_k)
// tile 128x128, BK=64, 4 waves, wave tile 64x64 (4x4 frags of 16x16x32)
using bf16x8 = __attribute__((ext_vector_type(8))) short;
using f32x4  = __attribute__((ext_vector_type(4))) float;

__global__ __launch_bounds__(256) void mm_argmin_kernel(
    const u16* __restrict__ Xh, const u16* __restrict__ Wh,
    const float* __restrict__ wnorm, u64* __restrict__ best) {
  __shared__ __align__(16) u16 As[128 * 64];
  __shared__ __align__(16) u16 Bs[128 * 64];
  const int t = threadIdx.x;
  const int w = t >> 6, l = t & 63;
  const int bid = blockIdx.x;
  const int rb = bid >> 3, cb = bid & 7;   // 8 code-blocks adjacent -> LLC reuse of A
  const size_t arow0 = (size_t)rb * 128;
  const int ccol0 = cb * 128;
  const int wr = w >> 1, wc = w & 1;       // wave tile origin (64x64)

  f32x4 acc[4][4] = {};

  const u16* Ag = Xh + arow0 * DIM;
  const u16* Bg = Wh + (size_t)ccol0 * DIM;
  // staging: 16 chunks of (8 rows x 64 dims); wave w owns chunks w*4..w*4+3
  const int srow = l >> 3;          // 0..7 within chunk
  const int sdim = (l & 7) * 8;     // 0,8,..,56

  for (int d0 = 0; d0 < DIM; d0 += 64) {
    __syncthreads();
#pragma unroll
    for (int c = 0; c < 4; ++c) {
      int chunk = w * 4 + c;
      int row = chunk * 8 + srow;
      gload_lds16(Ag + (size_t)row * DIM + d0 + sdim, &As[chunk * 512 + l * 8]);
      gload_lds16(Bg + (size_t)row * DIM + d0 + sdim, &Bs[chunk * 512 + l * 8]);
    }
    __syncthreads();
#pragma unroll
    for (int ks = 0; ks < 2; ++ks) {
      const int kof = ks * 32 + (l >> 4) * 8;
      bf16x8 af[4], bf[4];
#pragma unroll
      for (int m = 0; m < 4; ++m)
        af[m] = *(const bf16x8*)&As[(wr * 64 + m * 16 + (l & 15)) * 64 + kof];
#pragma unroll
      for (int n = 0; n < 4; ++n)
        bf[n] = *(const bf16x8*)&Bs[(wc * 64 + n * 16 + (l & 15)) * 64 + kof];
#pragma unroll
      for (int m = 0; m < 4; ++m)
#pragma unroll
        for (int n = 0; n < 4; ++n)
          acc[m][n] = __builtin_amdgcn_mfma_f32_16x16x32_bf16(af[m], bf[n], acc[m][n], 0, 0, 0);
    }
  }

  // epilogue: per-row argmin over this block's 128 codes, then global atomicMin
  const int cbase = ccol0 + wc * 64 + (l & 15);
  float wn[4];
#pragma unroll
  for (int n = 0; n < 4; ++n) wn[n] = wnorm[cbase + n * 16];
#pragma unroll
  for (int m = 0; m < 4; ++m) {
#pragma unroll
    for (int r = 0; r < 4; ++r) {
      u64 p = ~0ull;
#pragma unroll
      for (int n = 0; n < 4; ++n) {
        float s = fmaf(-2.0f, acc[m][n][r], wn[n]);
        unsigned u = __float_as_uint(s);
        unsigned key = (u & 0x80000000u) ? ~u : (u | 0x80000000u);
        u64 q = ((u64)key << 32) | (unsigned)(cbase + n * 16);
        if (q < p) p = q;
      }
#pragma unroll
      for (int off = 8; off; off >>= 1) {
        u64 o = __shfl_xor(p, off, 16);
        if (o < p) p = o;
      }
      if ((l & 15) == 0) {
        size_t row = arow0 + wr * 64 + m * 16 + (l >> 4) * 4 + r;
        atomicMin(best + row, p);
      }
    }
  }
}

// ---- post: unpack best -> idx, counts histogram, sum of best scores -------
__global__ __launch_bounds__(256) void post_kernel(const u64* __restrict__ best,
                                                   int* __restrict__ best_idx,
                                                   int* __restrict__ counts,
                                                   double* __restrict__ sumS) {
  int i = blockIdx.x * 256 + threadIdx.x;
  u64 p = best[i];
  int k = (int)(p & 0xffffffffu);
  unsigned key = (unsigned)(p >> 32);
  unsigned u = (key & 0x80000000u) ? (key ^ 0x80000000u) : ~key;
  float s = __uint_as_float(u);
  best_idx[i] = k;
  atomicAdd(&counts[k], 1);
  double d = (double)s;
#pragma unroll
  for (int off = 32; off; off >>= 1) d += __shfl_xor(d, off, 64);
  if ((threadIdx.x & 63) == 0) atomicAdd(sumS, d);
}

// ---- finalize: loss + perplexity ------------------------------------------
__global__ __launch_bounds__(256) void finalize_kernel(
    const int* __restrict__ counts, const double* __restrict__ sums,
    float* __restrict__ out_loss, float* __restrict__ out_perp) {
  __shared__ float red[4];
  int t = threadIdx.x;
  float h = 0.f;
  for (int k = t; k < KC; k += 256) {
    float p = (float)counts[k] / (float)NROWS;
    h -= p * logf(p + 1e-10f);
  }
#pragma unroll
  for (int off = 32; off; off >>= 1) h += __shfl_xor(h, off, 64);
  if ((t & 63) == 0) red[t >> 6] = h;
  __syncthreads();
  if (t == 0) {
    float H = red[0] + red[1] + red[2] + red[3];
    *out_perp = expf(H);
    double m = (sums[0] + sums[1]) / (double)((long long)NROWS * DIM);
    *out_loss = (float)(1.25 * m);
  }
}

// ---- quantized_st = W[best_idx] (scalar; d_out+1 only 4B-aligned) ---------
__global__ __launch_bounds__(256) void quant_kernel(const float* __restrict__ W,
                                                    const int* __restrict__ best_idx,
                                                    float* __restrict__ out) {
  int i0 = blockIdx.x * blockDim.x + threadIdx.x;
  int stride = gridDim.x * blockDim.x;
  const int total = NROWS * DIM;
  for (int i = i0; i < total; i += stride) {
    int row = i >> 9;
    int d = i & 511;
    out[i] = W[best_idx[row] * DIM + d];
  }
}

// ---- encodings one-hot ----------------------------------------------------
__global__ __launch_bounds__(256) void enc_kernel(const int* __restrict__ best_idx,
                                                  float2* __restrict__ out2) {
  int i0 = blockIdx.x * blockDim.x + threadIdx.x;
  int stride = gridDim.x * blockDim.x;
  const int total = NROWS * (KC / 2);
  for (int i = i0; i < total; i += stride) {
    int row = i >> 9;
    int c2 = i & 511;
    int k = best_idx[row];
    float2 v = {0.f, 0.f};
    if ((k >> 1) == c2) {
      if (k & 1) v.y = 1.0f; else v.x = 1.0f;
    }
    out2[i] = v;
  }
}

extern "C" void kernel_launch(void* const* d_in, const int* in_sizes, int n_in,
                              void* d_out, int out_size, void* d_ws, size_t ws_size,
                              hipStream_t stream) {
  const float* X = (const float*)d_in[0];
  const float* W = (const float*)d_in[1];
  float* out = (float*)d_out;
  char* ws = (char*)d_ws;

  float* out_loss = out;
  float* quant    = out + 1;
  float* out_perp = out + 1 + NROWS * DIM;
  float2* enc2    = (float2*)(out + 2 + NROWS * DIM);

  // big scratch lives inside the encodings output region (overwritten by
  // enc_kernel, which runs last): 16B-aligned start at float index 33554436
  char* sc = (char*)(out + 33554436);
  u16* Xh   = (u16*)sc;                       // 64 MB
  u16* Wh   = (u16*)(sc + (64u << 20));       // 1 MB
  u64* best = (u64*)(sc + (65u << 20));       // 512 KB

  int*    best_idx = (int*)ws;                 // 256 KB
  float*  wnorm    = (float*)(ws + (256 << 10));
  int*    counts   = (int*)(ws + (260 << 10));
  double* sums     = (double*)(ws + (264 << 10));  // [0]=sumX2 [1]=sumS

  hipMemsetAsync(best, 0xFF, NROWS * sizeof(u64), stream);
  hipMemsetAsync(ws + (260 << 10), 0, 4096 + 16, stream);

  convx_kernel<<<2048, 256, 0, stream>>>((const float4*)X, (ushort4*)Xh, &sums[0]);
  wprep_kernel<<<KC / 4, 256, 0, stream>>>(W, Wh, wnorm);
  mm_argmin_kernel<<<(NROWS / 128) * (KC / 128), 256, 0, stream>>>(Xh, Wh, wnorm, best);
  post_kernel<<<NROWS / 256, 256, 0, stream>>>(best, best_idx, counts, &sums[1]);
  finalize_kernel<<<1, 256, 0, stream>>>(counts, sums, out_loss, out_perp);
  quant_kernel<<<8192, 256, 0, stream>>>(W, best_idx, quant);
  enc_kernel<<<8192, 256, 0, stream>>>(best_idx, enc2);
}

// Round 4
// 283.635 us; speedup vs baseline: 3.7166x; 1.4043x over previous
//
#include <hip/hip_runtime.h>
#include <stdint.h>

typedef unsigned short u16;
typedef unsigned long long u64;
using short8 = __attribute__((ext_vector_type(8))) short;
using f32x4  = __attribute__((ext_vector_type(4))) float;

#define NROWS 65536
#define DIM   512
#define KC    1024

__device__ __forceinline__ u16 f2bf(float f) {  // RNE float->bf16 bits
  unsigned u = __float_as_uint(f);
  return (u16)((u + 0x7fffu + ((u >> 16) & 1u)) >> 16);
}

// ---- W prep: bf16 convert + exact ||w_k||^2 + zero counts/sums ------------
__global__ __launch_bounds__(256) void wprep_kernel(const float* __restrict__ W,
                                                    u16* __restrict__ Wh,
                                                    float* __restrict__ wnorm,
                                                    int* __restrict__ counts,
                                                    double* __restrict__ sums) {
  if (blockIdx.x == 0) {
    for (int k = threadIdx.x; k < KC; k += 256) counts[k] = 0;
    if (threadIdx.x < 2) sums[threadIdx.x] = 0.0;
  }
  int code = blockIdx.x * 4 + (threadIdx.x >> 6);
  int lane = threadIdx.x & 63;
  const float* wr = W + (size_t)code * DIM;
  u16* wh = Wh + (size_t)code * DIM;
  float s = 0.f;
#pragma unroll
  for (int j = 0; j < DIM / 64; ++j) {
    float v = wr[lane + j * 64];
    s = fmaf(v, v, s);
    wh[lane + j * 64] = f2bf(v);
  }
#pragma unroll
  for (int off = 32; off; off >>= 1) s += __shfl_xor(s, off, 64);
  if (lane == 0) wnorm[code] = s;
}

// ---- main: A(128x512) resident in swizzled LDS; kc-loop over all codes ----
// score_k(row) = ||w_k||^2_fp32 - 2 * dot_bf16(x_row, w_k); fused argmin,
// histogram, sum-of-best, sum(x^2). 512 thr = 8 waves, wave tile 32x64.
// Waves pair up: (wr, wc) — two waves per 32-row strip, one per 64-code half;
// their argmins are MERGED via LDS before the single output write (wc==0).
__global__ __launch_bounds__(512, 2) void mm_kernel(
    const float* __restrict__ X, const u16* __restrict__ Wh,
    const float* __restrict__ wnorm, int* __restrict__ best_idx,
    int* __restrict__ counts, double* __restrict__ sums) {
  __shared__ __align__(16) u16 As[128 * 512];  // 128 KB, chunk c at slot c^(row&7)
  __shared__ __align__(16) u16 Bs[128 * 64];   // 16 KB, same swizzle
  __shared__ u64 mbuf[4][32];                  // merge buffer: [wr][row-in-strip]
  const int t = threadIdx.x;
  const int w = t >> 6, l = t & 63;
  const int wr = w >> 1, wc = w & 1;     // wave tile origin: rows wr*32, cols wc*64
  const int lr = l & 15, lg = l >> 4;
  const int row0 = blockIdx.x * 128;

  // prefetch B phase 0 (kc=0,d0=0) into regs
  short8 nb[2];
#pragma unroll
  for (int g = 0; g < 2; ++g) {
    int slot = g * 512 + t;
    int row = slot >> 3, c = slot & 7;
    int cg = c ^ (row & 7);
    nb[g] = *(const short8*)&Wh[(size_t)row * DIM + cg * 8];
  }

  // stage A: fp32 -> bf16, swizzled ds_write, fused sum(x^2)
  double xacc = 0.0;
  const float4* Xg4 = (const float4*)X + (size_t)row0 * (DIM / 4);
#pragma unroll
  for (int j = 0; j < 16; ++j) {
    int f0 = j * 1024 + t * 2;
    float4 v0 = Xg4[f0];
    float4 v1 = Xg4[f0 + 1];
    xacc += (double)v0.x * v0.x + (double)v0.y * v0.y + (double)v0.z * v0.z + (double)v0.w * v0.w
          + (double)v1.x * v1.x + (double)v1.y * v1.y + (double)v1.z * v1.z + (double)v1.w * v1.w;
    short8 h;
    h[0] = (short)f2bf(v0.x); h[1] = (short)f2bf(v0.y);
    h[2] = (short)f2bf(v0.z); h[3] = (short)f2bf(v0.w);
    h[4] = (short)f2bf(v1.x); h[5] = (short)f2bf(v1.y);
    h[6] = (short)f2bf(v1.z); h[7] = (short)f2bf(v1.w);
    int row = f0 >> 7;               // 128 float4 per row
    int c = (f0 & 127) >> 1;         // 16B chunk 0..63
    int cs = c ^ (row & 7);
    *(short8*)&As[row * 512 + cs * 8] = h;
  }
#pragma unroll
  for (int off = 32; off; off >>= 1) xacc += __shfl_xor(xacc, off, 64);
  if (l == 0) atomicAdd(&sums[0], xacc);

#pragma unroll
  for (int g = 0; g < 2; ++g) *(short8*)&Bs[(g * 512 + t) * 8] = nb[g];
  __syncthreads();

  f32x4 acc[2][4] = {};
  u64 best[2][4];
#pragma unroll
  for (int m = 0; m < 2; ++m)
#pragma unroll
    for (int r = 0; r < 4; ++r) best[m][r] = ~0ull;
  const f32x4 vzero = {0.f, 0.f, 0.f, 0.f};

  for (int kc = 0; kc < 8; ++kc) {
    for (int d0 = 0; d0 < 8; ++d0) {
      const int p = kc * 8 + d0;
      const bool hasNext = p < 63;
      if (hasNext) {  // issue next-phase B loads early (latency hides under MFMA)
        int q = p + 1, qkc = q >> 3, qd0 = q & 7;
#pragma unroll
        for (int g = 0; g < 2; ++g) {
          int slot = g * 512 + t;
          int row = slot >> 3, c = slot & 7;
          int cg = c ^ (row & 7);
          nb[g] = *(const short8*)&Wh[(size_t)(qkc * 128 + row) * DIM + qd0 * 64 + cg * 8];
        }
      }
#pragma unroll
      for (int ks = 0; ks < 2; ++ks) {
        short8 af[2], bfr[4];
#pragma unroll
        for (int m = 0; m < 2; ++m) {
          int R = wr * 32 + m * 16 + lr;
          int c = d0 * 8 + ks * 4 + lg;
          int cs = c ^ (R & 7);
          af[m] = *(const short8*)&As[R * 512 + cs * 8];
        }
#pragma unroll
        for (int n = 0; n < 4; ++n) {
          int R = wc * 64 + n * 16 + lr;
          int c = ks * 4 + lg;
          int cs = c ^ (R & 7);
          bfr[n] = *(const short8*)&Bs[R * 64 + cs * 8];
        }
#pragma unroll
        for (int m = 0; m < 2; ++m)
#pragma unroll
          for (int n = 0; n < 4; ++n)
            acc[m][n] = __builtin_amdgcn_mfma_f32_16x16x32_bf16(af[m], bfr[n], acc[m][n], 0, 0, 0);
      }
      if (d0 == 7) {  // fold this kc-block's 128 codes into running argmin
        int cb = kc * 128 + wc * 64 + lr;
        float wn[4];
#pragma unroll
        for (int n = 0; n < 4; ++n) wn[n] = wnorm[cb + n * 16];
#pragma unroll
        for (int m = 0; m < 2; ++m)
#pragma unroll
          for (int r = 0; r < 4; ++r) {
            u64 pb = best[m][r];
#pragma unroll
            for (int n = 0; n < 4; ++n) {
              float s = fmaf(-2.0f, acc[m][n][r], wn[n]);
              unsigned u = __float_as_uint(s);
              unsigned key = (u & 0x80000000u) ? ~u : (u | 0x80000000u);
              u64 q = ((u64)key << 32) | (unsigned)(cb + n * 16);
              if (q < pb) pb = q;
            }
            best[m][r] = pb;
          }
#pragma unroll
        for (int m = 0; m < 2; ++m)
#pragma unroll
          for (int n = 0; n < 4; ++n) acc[m][n] = vzero;
      }
      __syncthreads();
      if (hasNext) {
#pragma unroll
        for (int g = 0; g < 2; ++g) *(short8*)&Bs[(g * 512 + t) * 8] = nb[g];
      }
      __syncthreads();
    }
  }

  // reduce across the 16 code-lanes within each wave
  u64 red[2][4];
#pragma unroll
  for (int m = 0; m < 2; ++m)
#pragma unroll
    for (int r = 0; r < 4; ++r) {
      u64 pb = best[m][r];
#pragma unroll
      for (int off = 8; off; off >>= 1) {
        u64 o = __shfl_xor(pb, off, 16);
        if (o < pb) pb = o;
      }
      red[m][r] = pb;
      if (wc == 1 && lr == 0) mbuf[wr][m * 16 + lg * 4 + r] = pb;
    }
  __syncthreads();

  // wc==0 waves merge the other half's result and write outputs (once per row)
  if (wc == 0) {
    double local = 0.0;
#pragma unroll
    for (int m = 0; m < 2; ++m)
#pragma unroll
      for (int r = 0; r < 4; ++r) {
        if (lr == 0) {
          u64 pb = red[m][r];
          u64 o = mbuf[wr][m * 16 + lg * 4 + r];
          if (o < pb) pb = o;
          int row = row0 + wr * 32 + m * 16 + lg * 4 + r;
          unsigned key = (unsigned)(pb >> 32);
          int k = (int)(pb & 0xffffffffu);
          best_idx[row] = k;
          atomicAdd(&counts[k], 1);
          unsigned uu = (key & 0x80000000u) ? (key ^ 0x80000000u) : ~key;
          local += (double)__uint_as_float(uu);
        }
      }
#pragma unroll
    for (int off = 32; off; off >>= 1) local += __shfl_xor(local, off, 64);
    if (l == 0) atomicAdd(&sums[1], local);
  }
}

// ---- finalize: loss + perplexity ------------------------------------------
__global__ __launch_bounds__(256) void finalize_kernel(
    const int* __restrict__ counts, const double* __restrict__ sums,
    float* __restrict__ out_loss, float* __restrict__ out_perp) {
  __shared__ float red[4];
  int t = threadIdx.x;
  float h = 0.f;
  for (int k = t; k < KC; k += 256) {
    float p = (float)counts[k] / (float)NROWS;
    h -= p * logf(p + 1e-10f);
  }
#pragma unroll
  for (int off = 32; off; off >>= 1) h += __shfl_xor(h, off, 64);
  if ((t & 63) == 0) red[t >> 6] = h;
  __syncthreads();
  if (t == 0) {
    float H = red[0] + red[1] + red[2] + red[3];
    *out_perp = expf(H);
    double m = (sums[0] + sums[1]) / (double)((long long)NROWS * DIM);
    *out_loss = (float)(1.25 * m);
  }
}

// ---- quantized_st = W[best_idx] (scalar; d_out+1 only 4B-aligned) ---------
__global__ __launch_bounds__(256) void quant_kernel(const float* __restrict__ W,
                                                    const int* __restrict__ best_idx,
                                                    float* __restrict__ out) {
  int i0 = blockIdx.x * blockDim.x + threadIdx.x;
  int stride = gridDim.x * blockDim.x;
  const int total = NROWS * DIM;
  for (int i = i0; i < total; i += stride) {
    int row = i >> 9;
    int d = i & 511;
    out[i] = W[best_idx[row] * DIM + d];
  }
}

// ---- encodings one-hot ----------------------------------------------------
__global__ __launch_bounds__(256) void enc_kernel(const int* __restrict__ best_idx,
                                                  float2* __restrict__ out2) {
  int i0 = blockIdx.x * blockDim.x + threadIdx.x;
  int stride = gridDim.x * blockDim.x;
  const int total = NROWS * (KC / 2);
  for (int i = i0; i < total; i += stride) {
    int row = i >> 9;
    int c2 = i & 511;
    int k = best_idx[row];
    float2 v = {0.f, 0.f};
    if ((k >> 1) == c2) {
      if (k & 1) v.y = 1.0f; else v.x = 1.0f;
    }
    out2[i] = v;
  }
}

extern "C" void kernel_launch(void* const* d_in, const int* in_sizes, int n_in,
                              void* d_out, int out_size, void* d_ws, size_t ws_size,
                              hipStream_t stream) {
  const float* X = (const float*)d_in[0];
  const float* W = (const float*)d_in[1];
  float* out = (float*)d_out;
  char* ws = (char*)d_ws;

  float* out_loss = out;                                // [0]
  float* quant    = out + 1;                            // [1 .. 1+N*D)
  float* out_perp = out + 1 + NROWS * DIM;              // [33554433]
  float2* enc2    = (float2*)(out + 2 + NROWS * DIM);   // 8B-aligned

  u16*    Wh       = (u16*)ws;                          // 1 MB
  float*  wnorm    = (float*)(ws + (1u << 20));         // 4 KB
  int*    counts   = (int*)(ws + (1u << 20) + 4096);    // 4 KB
  double* sums     = (double*)(ws + (1u << 20) + 8192); // 16 B  [0]=sumX2 [1]=sumS
  int*    best_idx = (int*)(ws + (1u << 20) + 12288);   // 256 KB

  wprep_kernel<<<KC / 4, 256, 0, stream>>>(W, Wh, wnorm, counts, sums);
  mm_kernel<<<NROWS / 128, 512, 0, stream>>>(X, Wh, wnorm, best_idx, counts, sums);
  finalize_kernel<<<1, 256, 0, stream>>>(counts, sums, out_loss, out_perp);
  quant_kernel<<<8192, 256, 0, stream>>>(W, best_idx, quant);
  enc_kernel<<<8192, 256, 0, stream>>>(best_idx, enc2);
}

// Round 5
// 251.519 us; speedup vs baseline: 4.1912x; 1.1277x over previous
//
#include <hip/hip_runtime.h>
#include <stdint.h>

typedef unsigned short u16;
typedef unsigned long long u64;
using short8 = __attribute__((ext_vector_type(8))) short;
using f32x16 = __attribute__((ext_vector_type(16))) float;

#define NROWS 65536
#define DIM   512
#define KC    1024

#define GLOBAL_AS __attribute__((address_space(1)))
#define LDS_AS    __attribute__((address_space(3)))

__device__ __forceinline__ void gload_lds16(const void* g, void* l) {
  __builtin_amdgcn_global_load_lds((const GLOBAL_AS uint32_t*)g,
                                   (LDS_AS uint32_t*)l, 16, 0, 0);
}

__device__ __forceinline__ u16 f2bf(float f) {  // RNE float->bf16 bits
  unsigned u = __float_as_uint(f);
  return (u16)((u + 0x7fffu + ((u >> 16) & 1u)) >> 16);
}

// ---- W prep: bf16 convert + exact ||w_k||^2 + zero counts/sums ------------
__global__ __launch_bounds__(256) void wprep_kernel(const float* __restrict__ W,
                                                    u16* __restrict__ Wh,
                                                    float* __restrict__ wnorm,
                                                    int* __restrict__ counts,
                                                    double* __restrict__ sums) {
  if (blockIdx.x == 0) {
    for (int k = threadIdx.x; k < KC; k += 256) counts[k] = 0;
    if (threadIdx.x < 2) sums[threadIdx.x] = 0.0;
  }
  int code = blockIdx.x * 4 + (threadIdx.x >> 6);
  int lane = threadIdx.x & 63;
  const float* wr = W + (size_t)code * DIM;
  u16* wh = Wh + (size_t)code * DIM;
  float s = 0.f;
#pragma unroll
  for (int j = 0; j < DIM / 64; ++j) {
    float v = wr[lane + j * 64];
    s = fmaf(v, v, s);
    wh[lane + j * 64] = f2bf(v);
  }
#pragma unroll
  for (int off = 32; off; off >>= 1) s += __shfl_xor(s, off, 64);
  if (lane == 0) wnorm[code] = s;
}

// ---- main: A-in-registers, B streamed through swizzled LDS, 32x32x16 MFMA -
// Block = 8 waves x 32 rows = 256 rows, grid = 256 (1 block/CU).
// Each wave: A rows in 128 VGPR (all K), loops over 16 kc-tiles of 64 codes.
// score = ||w||^2_fp32 - 2*dot_bf16; fused argmin/hist/sums.
#define FOLD(V, WN, COL, Q)                                                  \
  {                                                                          \
    float sc_ = fmaf(-2.0f, (V), (WN));                                      \
    unsigned u_ = __float_as_uint(sc_);                                      \
    unsigned k_ = (u_ & 0x80000000u) ? ~u_ : (u_ | 0x80000000u);             \
    u64 p_ = ((u64)k_ << 32) | (unsigned)(COL);                              \
    if (p_ < best_[Q]) best_[Q] = p_;                                        \
  }

#define KCBODY(KCV, BUF)                                                     \
  {                                                                          \
    const int kc_ = (KCV);                                                   \
    if (kc_ < 15) { /* prefetch next B tile into other buffer */             \
      const u16* nsrc = Wh + (size_t)(kc_ + 1) * 32768 + w * 4096;           \
      _Pragma("unroll")                                                      \
      for (int i = 0; i < 8; ++i)                                            \
        gload_lds16(nsrc + i * 512 + ((l ^ i) * 8),                          \
                    &Bs[(BUF) ^ 1][w * 8 + i][l * 8]);                       \
    }                                                                        \
    float wn0 = wnorm[kc_ * 64 + r];                                         \
    float wn1 = wnorm[kc_ * 64 + 32 + r];                                    \
    f32x16 acc0 = {}, acc1 = {};                                             \
    _Pragma("unroll")                                                        \
    for (int s = 0; s < 32; ++s) {                                           \
      short8 b0 = *(const short8*)&BsF[bb[(BUF)][0][s & 3] + (s >> 2) * 64]; \
      short8 b1 = *(const short8*)&BsF[bb[(BUF)][1][s & 3] + (s >> 2) * 64]; \
      acc0 = __builtin_amdgcn_mfma_f32_32x32x16_bf16(aF[s], b0, acc0, 0, 0, 0); \
      acc1 = __builtin_amdgcn_mfma_f32_32x32x16_bf16(aF[s], b1, acc1, 0, 0, 0); \
    }                                                                        \
    int col0 = kc_ * 64 + r;                                                 \
    _Pragma("unroll")                                                        \
    for (int q = 0; q < 16; ++q) {                                           \
      FOLD(acc0[q], wn0, col0, q);                                           \
      FOLD(acc1[q], wn1, col0 + 32, q);                                      \
    }                                                                        \
    __syncthreads();                                                         \
  }

__global__ __launch_bounds__(512, 2) void mm_kernel(
    const float* __restrict__ X, const u16* __restrict__ Wh,
    const float* __restrict__ wnorm, int* __restrict__ best_idx,
    int* __restrict__ counts, double* __restrict__ sums) {
  __shared__ __align__(16) u16 Bs[2][64][512];  // 128 KB, chunk c at c^(row&7)
  u16* BsF = (u16*)Bs;
  const int t = threadIdx.x;
  const int w = t >> 6, l = t & 63;
  const int r = l & 31, h = l >> 5;      // MFMA lane decomposition
  const int row0 = blockIdx.x * 256;

  // kick off B tile kc=0 into buf0 (source pre-swizzled, dest linear)
#pragma unroll
  for (int i = 0; i < 8; ++i)
    gload_lds16(Wh + (size_t)w * 4096 + i * 512 + ((l ^ i) * 8),
                &Bs[0][w * 8 + i][l * 8]);

  // load my A row half into registers (bf16), fused sum(x^2)
  const float* Xr = X + (size_t)(row0 + w * 32 + r) * DIM + h * 8;
  short8 aF[32];
  double xacc = 0.0;
#pragma unroll
  for (int s = 0; s < 32; ++s) {
    float4 v0 = *(const float4*)(Xr + s * 16);
    float4 v1 = *(const float4*)(Xr + s * 16 + 4);
    xacc += (double)v0.x * v0.x + (double)v0.y * v0.y + (double)v0.z * v0.z + (double)v0.w * v0.w
          + (double)v1.x * v1.x + (double)v1.y * v1.y + (double)v1.z * v1.z + (double)v1.w * v1.w;
    short8 pk;
    pk[0] = (short)f2bf(v0.x); pk[1] = (short)f2bf(v0.y);
    pk[2] = (short)f2bf(v0.z); pk[3] = (short)f2bf(v0.w);
    pk[4] = (short)f2bf(v1.x); pk[5] = (short)f2bf(v1.y);
    pk[6] = (short)f2bf(v1.z); pk[7] = (short)f2bf(v1.w);
    aF[s] = pk;
  }
#pragma unroll
  for (int off = 32; off; off >>= 1) xacc += __shfl_xor(xacc, off, 64);
  if (l == 0) atomicAdd(&sums[0], xacc);

  // precomputed ds_read bases: [buf][cc][s&3] (element idx into BsF)
  int bb[2][2][4];
#pragma unroll
  for (int bu = 0; bu < 2; ++bu)
#pragma unroll
    for (int cc = 0; cc < 2; ++cc)
#pragma unroll
      for (int b = 0; b < 4; ++b)
        bb[bu][cc][b] = bu * 32768 + (cc * 32 + r) * 512 +
                        (((2 * b + h) ^ (r & 7)) * 8);

  u64 best_[16];
#pragma unroll
  for (int q = 0; q < 16; ++q) best_[q] = ~0ull;

  __syncthreads();  // B tile 0 ready (drains vmcnt)

  for (int kc2 = 0; kc2 < 8; ++kc2) {
    KCBODY(kc2 * 2, 0)
    KCBODY(kc2 * 2 + 1, 1)
  }

  // cross-lane argmin over the 32 col-lanes (same h half), then outputs
  double local = 0.0;
#pragma unroll
  for (int q = 0; q < 16; ++q) {
    u64 pb = best_[q];
#pragma unroll
    for (int off = 16; off; off >>= 1) {
      u64 o = __shfl_xor(pb, off, 32);
      if (o < pb) pb = o;
    }
    if (r == 0) {
      int row = row0 + w * 32 + (q & 3) + 8 * (q >> 2) + 4 * h;
      unsigned key = (unsigned)(pb >> 32);
      int k = (int)(pb & 0xffffffffu);
      best_idx[row] = k;
      atomicAdd(&counts[k], 1);
      unsigned uu = (key & 0x80000000u) ? (key ^ 0x80000000u) : ~key;
      local += (double)__uint_as_float(uu);
    }
  }
  if (r == 0) atomicAdd(&sums[1], local);
}

// ---- finalize: loss + perplexity ------------------------------------------
__global__ __launch_bounds__(256) void finalize_kernel(
    const int* __restrict__ counts, const double* __restrict__ sums,
    float* __restrict__ out_loss, float* __restrict__ out_perp) {
  __shared__ float red[4];
  int t = threadIdx.x;
  float h = 0.f;
  for (int k = t; k < KC; k += 256) {
    float p = (float)counts[k] / (float)NROWS;
    h -= p * logf(p + 1e-10f);
  }
#pragma unroll
  for (int off = 32; off; off >>= 1) h += __shfl_xor(h, off, 64);
  if ((t & 63) == 0) red[t >> 6] = h;
  __syncthreads();
  if (t == 0) {
    float H = red[0] + red[1] + red[2] + red[3];
    *out_perp = expf(H);
    double m = (sums[0] + sums[1]) / (double)((long long)NROWS * DIM);
    *out_loss = (float)(1.25 * m);
  }
}

// ---- quantized_st = W[best_idx] (scalar; d_out+1 only 4B-aligned) ---------
__global__ __launch_bounds__(256) void quant_kernel(const float* __restrict__ W,
                                                    const int* __restrict__ best_idx,
                                                    float* __restrict__ out) {
  int i0 = blockIdx.x * blockDim.x + threadIdx.x;
  int stride = gridDim.x * blockDim.x;
  const int total = NROWS * DIM;
  for (int i = i0; i < total; i += stride) {
    int row = i >> 9;
    int d = i & 511;
    out[i] = W[best_idx[row] * DIM + d];
  }
}

// ---- encodings one-hot ----------------------------------------------------
__global__ __launch_bounds__(256) void enc_kernel(const int* __restrict__ best_idx,
                                                  float2* __restrict__ out2) {
  int i0 = blockIdx.x * blockDim.x + threadIdx.x;
  int stride = gridDim.x * blockDim.x;
  const int total = NROWS * (KC / 2);
  for (int i = i0; i < total; i += stride) {
    int row = i >> 9;
    int c2 = i & 511;
    int k = best_idx[row];
    float2 v = {0.f, 0.f};
    if ((k >> 1) == c2) {
      if (k & 1) v.y = 1.0f; else v.x = 1.0f;
    }
    out2[i] = v;
  }
}

extern "C" void kernel_launch(void* const* d_in, const int* in_sizes, int n_in,
                              void* d_out, int out_size, void* d_ws, size_t ws_size,
                              hipStream_t stream) {
  const float* X = (const float*)d_in[0];
  const float* W = (const float*)d_in[1];
  float* out = (float*)d_out;
  char* ws = (char*)d_ws;

  float* out_loss = out;                                // [0]
  float* quant    = out + 1;                            // [1 .. 1+N*D)
  float* out_perp = out + 1 + NROWS * DIM;              // [33554433]
  float2* enc2    = (float2*)(out + 2 + NROWS * DIM);   // 8B-aligned

  u16*    Wh       = (u16*)ws;                          // 1 MB
  float*  wnorm    = (float*)(ws + (1u << 20));         // 4 KB
  int*    counts   = (int*)(ws + (1u << 20) + 4096);    // 4 KB
  double* sums     = (double*)(ws + (1u << 20) + 8192); // [0]=sumX2 [1]=sumS
  int*    best_idx = (int*)(ws + (1u << 20) + 12288);   // 256 KB

  wprep_kernel<<<KC / 4, 256, 0, stream>>>(W, Wh, wnorm, counts, sums);
  mm_kernel<<<NROWS / 256, 512, 0, stream>>>(X, Wh, wnorm, best_idx, counts, sums);
  finalize_kernel<<<1, 256, 0, stream>>>(counts, sums, out_loss, out_perp);
  quant_kernel<<<8192, 256, 0, stream>>>(W, best_idx, quant);
  enc_kernel<<<8192, 256, 0, stream>>>(best_idx, enc2);
}

// Round 6
// 227.047 us; speedup vs baseline: 4.6429x; 1.1078x over previous
//
#include <hip/hip_runtime.h>
#include <stdint.h>

typedef unsigned short u16;
typedef unsigned long long u64;
using short8 = __attribute__((ext_vector_type(8))) short;
using f32x16 = __attribute__((ext_vector_type(16))) float;

#define NROWS 65536
#define DIM   512
#define KC    1024

#define GLOBAL_AS __attribute__((address_space(1)))
#define LDS_AS    __attribute__((address_space(3)))

__device__ __forceinline__ void gload_lds16(const void* g, void* l) {
  __builtin_amdgcn_global_load_lds((const GLOBAL_AS uint32_t*)g,
                                   (LDS_AS uint32_t*)l, 16, 0, 0);
}

__device__ __forceinline__ u16 f2bf(float f) {  // RNE float->bf16 bits
  unsigned u = __float_as_uint(f);
  return (u16)((u + 0x7fffu + ((u >> 16) & 1u)) >> 16);
}

// ---- W prep: bf16 convert + exact ||w_k||^2 + zero counts/sums ------------
__global__ __launch_bounds__(256) void wprep_kernel(const float* __restrict__ W,
                                                    u16* __restrict__ Wh,
                                                    float* __restrict__ wnorm,
                                                    int* __restrict__ counts,
                                                    double* __restrict__ sums) {
  if (blockIdx.x == 0) {
    for (int k = threadIdx.x; k < KC; k += 256) counts[k] = 0;
    if (threadIdx.x < 2) sums[threadIdx.x] = 0.0;
  }
  int code = blockIdx.x * 4 + (threadIdx.x >> 6);
  int lane = threadIdx.x & 63;
  const float* wr = W + (size_t)code * DIM;
  u16* wh = Wh + (size_t)code * DIM;
  float s = 0.f;
#pragma unroll
  for (int j = 0; j < DIM / 64; ++j) {
    float v = wr[lane + j * 64];
    s = fmaf(v, v, s);
    wh[lane + j * 64] = f2bf(v);
  }
#pragma unroll
  for (int off = 32; off; off >>= 1) s += __shfl_xor(s, off, 64);
  if (lane == 0) wnorm[code] = s;
}

// ---- main fused kernel ----------------------------------------------------
// 256 thr = 4 waves, 2 blocks/CU, block = 128 rows. A (32 rows x 512) in regs
// per wave; B streams 32-code tiles through double-buffered swizzled LDS.
// Fused: argmin, histogram, sums, quantized gather-write, one-hot write
// (zeros streamed during compute, 1.0 scatter at end).
#define KCBODY(KCV, BUF)                                                       \
  {                                                                            \
    const int kc_ = (KCV);                                                     \
    if (kc_ < 31) { /* prefetch next 32-code tile into other buffer */         \
      const u16* nsrc = Wh + ((size_t)(kc_ + 1) * 32 + w * 8) * 512;           \
      _Pragma("unroll")                                                        \
      for (int i = 0; i < 8; ++i)                                              \
        gload_lds16(nsrc + (size_t)i * 512 + ((l ^ i) * 8),                    \
                    &BsU[(w * 8 + i) * 1024 + ((BUF) ^ 1) * 512 + l * 8]);     \
    }                                                                          \
    _Pragma("unroll")                                                          \
    for (int j = 0; j < 8; ++j) /* stream one-hot zeros (16 KB/tile) */        \
      encz[kc_ * 2048 + j * 256 + t] = zero2;                                  \
    f32x16 acc = {};                                                           \
    _Pragma("unroll")                                                          \
    for (int ph = 0; ph < 8; ++ph) {                                           \
      short8 bv[4];                                                            \
      _Pragma("unroll")                                                        \
      for (int j = 0; j < 4; ++j)                                              \
        bv[j] = *(const short8*)&BsU[eb[j] + ((BUF) * 512 + ph * 64)];         \
      __builtin_amdgcn_s_setprio(1);                                           \
      _Pragma("unroll")                                                        \
      for (int j = 0; j < 4; ++j)                                              \
        acc = __builtin_amdgcn_mfma_f32_32x32x16_bf16(aF[ph * 4 + j], bv[j],   \
                                                      acc, 0, 0, 0);           \
      __builtin_amdgcn_s_setprio(0);                                           \
    }                                                                          \
    float wn = wnorm[kc_ * 32 + r];                                            \
    unsigned col = (unsigned)(kc_ * 32 + r);                                   \
    _Pragma("unroll")                                                          \
    for (int q = 0; q < 16; ++q) {                                             \
      float sc = fmaf(-2.0f, acc[q], wn);                                      \
      unsigned u_ = __float_as_uint(sc);                                       \
      unsigned key = (u_ & 0x80000000u) ? ~u_ : (u_ | 0x80000000u);            \
      u64 p_ = ((u64)key << 32) | col;                                         \
      if (p_ < best_[q]) best_[q] = p_;                                        \
    }                                                                          \
    __syncthreads();                                                           \
  }

__global__ __launch_bounds__(256, 2) void mm_kernel(
    const float* __restrict__ X, const float* __restrict__ W,
    const u16* __restrict__ Wh, const float* __restrict__ wnorm,
    int* __restrict__ counts, double* __restrict__ sums,
    float* __restrict__ quant, float* __restrict__ encf) {
  __shared__ __align__(16) u16 BsU[32 * 1024];  // [code][buf][512] = 64 KB
  __shared__ int rowk[128];
  __shared__ double sdbl[4];
  const int t = threadIdx.x;
  const int w = t >> 6, l = t & 63;
  const int r = l & 31, h = l >> 5;
  const int row0 = blockIdx.x * 128;
  const float2 zero2 = {0.f, 0.f};
  float2* encz = (float2*)(encf + (size_t)row0 * KC);

  // kick off B tile 0 into buf 0 (pre-swizzled source, linear dest)
  {
    const u16* src0 = Wh + (size_t)(w * 8) * 512;
#pragma unroll
    for (int i = 0; i < 8; ++i)
      gload_lds16(src0 + (size_t)i * 512 + ((l ^ i) * 8),
                  &BsU[(w * 8 + i) * 1024 + l * 8]);
  }

  // A panel (32 rows x 512) -> registers, bf16, fused sum(x^2)
  const float* Xr = X + (size_t)(row0 + w * 32 + r) * DIM + h * 8;
  short8 aF[32];
  double xacc = 0.0;
#pragma unroll
  for (int s = 0; s < 32; ++s) {
    float4 v0 = *(const float4*)(Xr + s * 16);
    float4 v1 = *(const float4*)(Xr + s * 16 + 4);
    xacc += (double)v0.x * v0.x + (double)v0.y * v0.y + (double)v0.z * v0.z + (double)v0.w * v0.w
          + (double)v1.x * v1.x + (double)v1.y * v1.y + (double)v1.z * v1.z + (double)v1.w * v1.w;
    short8 pk;
    pk[0] = (short)f2bf(v0.x); pk[1] = (short)f2bf(v0.y);
    pk[2] = (short)f2bf(v0.z); pk[3] = (short)f2bf(v0.w);
    pk[4] = (short)f2bf(v1.x); pk[5] = (short)f2bf(v1.y);
    pk[6] = (short)f2bf(v1.z); pk[7] = (short)f2bf(v1.w);
    aF[s] = pk;
  }
#pragma unroll
  for (int off = 32; off; off >>= 1) xacc += __shfl_xor(xacc, off, 64);
  if (l == 0) atomicAdd(&sums[0], xacc);

  // ds_read bases: elem = r*1024 + f*8 + 16*((s&3)^e)  [+ buf*512 + (s>>2)*64]
  const int e = (r & 7) >> 1;
  const int f = h ^ (r & 1);
  int eb[4];
#pragma unroll
  for (int j = 0; j < 4; ++j) eb[j] = r * 1024 + f * 8 + ((j ^ e) * 16);

  u64 best_[16];
#pragma unroll
  for (int q = 0; q < 16; ++q) best_[q] = ~0ull;

  __syncthreads();  // tile 0 resident

  for (int kc2 = 0; kc2 < 16; ++kc2) {
    KCBODY(kc2 * 2, 0)
    KCBODY(kc2 * 2 + 1, 1)
  }

  // per-row argmin across the 32 code-lanes; outputs
  double local = 0.0;
#pragma unroll
  for (int q = 0; q < 16; ++q) {
    u64 pb = best_[q];
#pragma unroll
    for (int off = 16; off; off >>= 1) {
      u64 o = __shfl_xor(pb, off, 32);
      if (o < pb) pb = o;
    }
    if (r == 0) {
      int rit = w * 32 + (q & 3) + 8 * (q >> 2) + 4 * h;
      int k = (int)(pb & 0xffffffffu);
      rowk[rit] = k;
      atomicAdd(&counts[k], 1);
      unsigned key = (unsigned)(pb >> 32);
      unsigned uu = (key & 0x80000000u) ? (key ^ 0x80000000u) : ~key;
      local += (double)__uint_as_float(uu);
    }
  }
  {
    double o32 = __shfl(local, 32, 64);
    if (l == 0) sdbl[w] = local + o32;
  }
  __syncthreads();
  if (t == 0) atomicAdd(&sums[1], sdbl[0] + sdbl[1] + sdbl[2] + sdbl[3]);

  // fused quantized gather-write (scalar stores: quant base is 4B-aligned)
  // + one-hot 1.0 scatter (zeros already streamed during the kc-loop)
  for (int j = 0; j < 32; ++j) {
    int rit = w * 32 + j;
    int k = rowk[rit];
    size_t row = (size_t)(row0 + rit);
    float4 wv0 = *(const float4*)&W[(size_t)k * DIM + l * 8];
    float4 wv1 = *(const float4*)&W[(size_t)k * DIM + l * 8 + 4];
    float* dst = quant + row * DIM + l * 8;
    dst[0] = wv0.x; dst[1] = wv0.y; dst[2] = wv0.z; dst[3] = wv0.w;
    dst[4] = wv1.x; dst[5] = wv1.y; dst[6] = wv1.z; dst[7] = wv1.w;
    if (l == 0) encf[row * KC + k] = 1.0f;
  }
}

// ---- finalize: loss + perplexity ------------------------------------------
__global__ __launch_bounds__(256) void finalize_kernel(
    const int* __restrict__ counts, const double* __restrict__ sums,
    float* __restrict__ out_loss, float* __restrict__ out_perp) {
  __shared__ float red[4];
  int t = threadIdx.x;
  float h = 0.f;
  for (int k = t; k < KC; k += 256) {
    float p = (float)counts[k] / (float)NROWS;
    h -= p * logf(p + 1e-10f);
  }
#pragma unroll
  for (int off = 32; off; off >>= 1) h += __shfl_xor(h, off, 64);
  if ((t & 63) == 0) red[t >> 6] = h;
  __syncthreads();
  if (t == 0) {
    float H = red[0] + red[1] + red[2] + red[3];
    *out_perp = expf(H);
    double m = (sums[0] + sums[1]) / (double)((long long)NROWS * DIM);
    *out_loss = (float)(1.25 * m);
  }
}

extern "C" void kernel_launch(void* const* d_in, const int* in_sizes, int n_in,
                              void* d_out, int out_size, void* d_ws, size_t ws_size,
                              hipStream_t stream) {
  const float* X = (const float*)d_in[0];
  const float* W = (const float*)d_in[1];
  float* out = (float*)d_out;
  char* ws = (char*)d_ws;

  float* out_loss = out;                     // [0]
  float* quant    = out + 1;                 // [1 .. 1+N*D)
  float* out_perp = out + 1 + NROWS * DIM;   // [33554433]
  float* encf     = out + 2 + NROWS * DIM;   // [33554434 ..), 8B-aligned

  u16*    Wh     = (u16*)ws;                          // 1 MB
  float*  wnorm  = (float*)(ws + (1u << 20));         // 4 KB
  int*    counts = (int*)(ws + (1u << 20) + 4096);    // 4 KB
  double* sums   = (double*)(ws + (1u << 20) + 8192); // [0]=sumX2 [1]=sumS

  wprep_kernel<<<KC / 4, 256, 0, stream>>>(W, Wh, wnorm, counts, sums);
  mm_kernel<<<NROWS / 128, 256, 0, stream>>>(X, W, Wh, wnorm, counts, sums,
                                             quant, encf);
  finalize_kernel<<<1, 256, 0, stream>>>(counts, sums, out_loss, out_perp);
}